// Round 1
// baseline (157.690 us; speedup 1.0000x reference)
//
#include <hip/hip_runtime.h>
#include <hip/hip_bf16.h>

typedef __attribute__((ext_vector_type(8))) short short8;
typedef __attribute__((ext_vector_type(4))) float f32x4;

#define H_DIM 768
#define E_EXP 16
#define T_TASK 8
#define KSEL 4
#define L_SEQ 8192
#define B_BATCH 16
#define EW_STRIDE (768*768)

// ---------------------------------------------------------------- gating ----
__global__ void gating_kernel(const float* __restrict__ task_full,
                              const float* __restrict__ gate_w,
                              const float* __restrict__ gate_b,
                              float* __restrict__ out_tail,   // [16 active_probs][8*16 one-hot]
                              float* __restrict__ ws_gates,
                              int*   __restrict__ ws_idx) {
  __shared__ float silu_s[T_TASK * H_DIM];
  __shared__ float logits[T_TASK][E_EXP];
  const int tid = threadIdx.x;  // 256 threads
  for (int i = tid; i < T_TASK * H_DIM; i += 256) {
    float v = task_full[i];
    silu_s[i] = v / (1.f + expf(-v));
  }
  __syncthreads();
  if (tid < T_TASK * E_EXP) {
    const int t = tid >> 4, e = tid & 15;
    float a0 = 0.f, a1 = 0.f, a2 = 0.f, a3 = 0.f;
    const float* sl = &silu_s[t * H_DIM];
    for (int h = 0; h < H_DIM; h += 4) {
      a0 += sl[h]     * gate_w[(h)     * E_EXP + e];
      a1 += sl[h + 1] * gate_w[(h + 1) * E_EXP + e];
      a2 += sl[h + 2] * gate_w[(h + 2) * E_EXP + e];
      a3 += sl[h + 3] * gate_w[(h + 3) * E_EXP + e];
    }
    logits[t][e] = (a0 + a1) + (a2 + a3) + gate_b[e];
  }
  __syncthreads();
  if (tid < T_TASK) {
    const int t = tid;
    float p[E_EXP];
    float m = -1e30f;
    for (int e = 0; e < E_EXP; ++e) m = fmaxf(m, logits[t][e]);
    float s = 0.f;
    for (int e = 0; e < E_EXP; ++e) { p[e] = expf(logits[t][e] - m); s += p[e]; }
    const float inv = 1.f / s;
    for (int e = 0; e < E_EXP; ++e) p[e] *= inv;
    // top-4, strict > keeps lowest index on ties (lax.top_k semantics)
    bool used[E_EXP];
    for (int e = 0; e < E_EXP; ++e) used[e] = false;
    float g[KSEL]; int sel[KSEL];
    for (int k = 0; k < KSEL; ++k) {
      float bv = -1.f; int bi = 0;
      for (int e = 0; e < E_EXP; ++e)
        if (!used[e] && p[e] > bv) { bv = p[e]; bi = e; }
      used[bi] = true; sel[k] = bi; g[k] = bv;
    }
    for (int e = 0; e < E_EXP; ++e)
      out_tail[E_EXP + t * E_EXP + e] = used[e] ? 1.f : 0.f;
    if (t == 0) {
      for (int e = 0; e < E_EXP; ++e) out_tail[e] = p[e];
      for (int k = 0; k < KSEL; ++k) { ws_gates[k] = g[k]; ws_idx[k] = sel[k]; }
    }
  }
}

// ------------------------------------------------- combined weight (T) ------
// wct[o][d] = sum_k gates[k] * expert_w[idx[k]][d][o], bf16
__global__ void build_wct_kernel(const float* __restrict__ expert_w,
                                 const float* __restrict__ gates,
                                 const int* __restrict__ idx,
                                 __hip_bfloat16* __restrict__ wct) {
  __shared__ float tile[32][33];
  const int d0 = blockIdx.x * 32, o0 = blockIdx.y * 32;
  const float g0 = gates[0], g1 = gates[1], g2 = gates[2], g3 = gates[3];
  const size_t e0 = (size_t)idx[0] * EW_STRIDE;
  const size_t e1 = (size_t)idx[1] * EW_STRIDE;
  const size_t e2 = (size_t)idx[2] * EW_STRIDE;
  const size_t e3 = (size_t)idx[3] * EW_STRIDE;
  const int c = threadIdx.x & 31;
  const int r0 = threadIdx.x >> 5;  // 0..7
#pragma unroll
  for (int it = 0; it < 4; ++it) {
    const int rr = it * 8 + r0;  // d offset
    const size_t off = (size_t)(d0 + rr) * H_DIM + o0 + c;
    tile[rr][c] = g0 * expert_w[e0 + off] + g1 * expert_w[e1 + off] +
                  g2 * expert_w[e2 + off] + g3 * expert_w[e3 + off];
  }
  __syncthreads();
#pragma unroll
  for (int it = 0; it < 4; ++it) {
    const int rr = it * 8 + r0;  // o offset
    wct[(size_t)(o0 + rr) * H_DIM + d0 + c] = __float2bfloat16(tile[c][rr]);
  }
}

// ------------------------------------------------------------ x0 -> bf16 ----
__global__ void cvt_x0_kernel(const float4* __restrict__ x, uint4* __restrict__ xb) {
  const int i = blockIdx.x * blockDim.x + threadIdx.x;  // one uint4 = 8 bf16
  const float4 a = x[2 * i];
  const float4 b = x[2 * i + 1];
  alignas(16) __hip_bfloat16 h[8];
  h[0] = __float2bfloat16(a.x); h[1] = __float2bfloat16(a.y);
  h[2] = __float2bfloat16(a.z); h[3] = __float2bfloat16(a.w);
  h[4] = __float2bfloat16(b.x); h[5] = __float2bfloat16(b.y);
  h[6] = __float2bfloat16(b.z); h[7] = __float2bfloat16(b.w);
  xb[i] = *(const uint4*)h;
}

// ----------------------------------------------------------------- GEMM -----
__device__ __forceinline__ void gload_lds16(const void* g, void* l) {
  __builtin_amdgcn_global_load_lds((const __attribute__((address_space(1))) void*)g,
                                   (__attribute__((address_space(3))) void*)l, 16, 0, 0);
}

// C[l][o] = 1 + sum_d A[l][d] * Bt[o][d];  A:[8192][768] bf16, Bt:[768][768] bf16
__global__ __launch_bounds__(256) void gemm_kernel(
    const __hip_bfloat16* __restrict__ A,
    const __hip_bfloat16* __restrict__ Bt,
    float* __restrict__ C) {
  __shared__ __hip_bfloat16 As[128 * 32];
  __shared__ __hip_bfloat16 Bs[128 * 32];
  const int tid = threadIdx.x;
  const int m0 = blockIdx.x * 128;
  const int n0 = blockIdx.y * 128;
  const int lane = tid & 63;
  const int w = tid >> 6;
  const int wr = w >> 1, wc = w & 1;       // 2x2 wave grid, 64x64 each
  const int r = tid >> 2, s = tid & 3;     // staging: row, 16B chunk
  const __hip_bfloat16* ga = A  + (size_t)(m0 + r) * H_DIM + s * 8;
  const __hip_bfloat16* gb = Bt + (size_t)(n0 + r) * H_DIM + s * 8;
  f32x4 acc[4][4] = {};
  const int arow = wr * 64 + (lane & 15);
  const int brow = wc * 64 + (lane & 15);
  const int koff = (lane >> 4) * 8;  // same k mapping for A and B -> k-perm safe
  for (int k0 = 0; k0 < H_DIM; k0 += 32) {
    gload_lds16(ga + k0,               &As[tid * 8]);
    gload_lds16(ga + 64 * H_DIM + k0,  &As[2048 + tid * 8]);
    gload_lds16(gb + k0,               &Bs[tid * 8]);
    gload_lds16(gb + 64 * H_DIM + k0,  &Bs[2048 + tid * 8]);
    __syncthreads();
    short8 av[4], bv[4];
#pragma unroll
    for (int i = 0; i < 4; ++i) av[i] = *(const short8*)&As[(arow + i * 16) * 32 + koff];
#pragma unroll
    for (int j = 0; j < 4; ++j) bv[j] = *(const short8*)&Bs[(brow + j * 16) * 32 + koff];
#pragma unroll
    for (int i = 0; i < 4; ++i)
#pragma unroll
      for (int j = 0; j < 4; ++j)
        acc[i][j] = __builtin_amdgcn_mfma_f32_16x16x32_bf16(av[i], bv[j], acc[i][j], 0, 0, 0);
    __syncthreads();
  }
  const int crow0 = m0 + wr * 64 + (lane >> 4) * 4;
  const int ccol0 = n0 + wc * 64 + (lane & 15);
#pragma unroll
  for (int i = 0; i < 4; ++i)
#pragma unroll
    for (int j = 0; j < 4; ++j)
#pragma unroll
      for (int q = 0; q < 4; ++q)
        C[(size_t)(crow0 + i * 16 + q) * H_DIM + ccol0 + j * 16] = 1.0f + acc[i][j][q];
}

// ----------------------------------------------------------------- fill -----
__global__ void fill_ones_kernel(float4* __restrict__ p, size_t n4) {
  size_t i = (size_t)blockIdx.x * blockDim.x + threadIdx.x;
  const size_t stride = (size_t)gridDim.x * blockDim.x;
  const float4 one = make_float4(1.f, 1.f, 1.f, 1.f);
  for (; i < n4; i += stride) p[i] = one;
}

// ---------------------------------------------------------------- launch ----
extern "C" void kernel_launch(void* const* d_in, const int* in_sizes, int n_in,
                              void* d_out, int out_size, void* d_ws, size_t ws_size,
                              hipStream_t stream) {
  const float* x         = (const float*)d_in[0];  // [16][8192][768]
  const float* task_full = (const float*)d_in[1];  // [8][768]
  const float* gate_w    = (const float*)d_in[2];  // [768][16]
  const float* gate_b    = (const float*)d_in[3];  // [16]
  const float* expert_w  = (const float*)d_in[4];  // [16][768][768]
  float* out = (float*)d_out;

  const size_t n_out_main = (size_t)B_BATCH * L_SEQ * H_DIM;  // 100663296
  float* out_tail = out + n_out_main;

  float* ws_gates = (float*)d_ws;
  int*   ws_idx   = (int*)((char*)d_ws + 16);
  __hip_bfloat16* wct = (__hip_bfloat16*)((char*)d_ws + 512);
  __hip_bfloat16* x0b = (__hip_bfloat16*)((char*)d_ws + 512 + (size_t)EW_STRIDE * 2);

  // 1. gating (tiny)
  gating_kernel<<<1, 256, 0, stream>>>(task_full, gate_w, gate_b, out_tail, ws_gates, ws_idx);
  // 2. x0 -> bf16 (independent of gating)
  cvt_x0_kernel<<<(L_SEQ * H_DIM / 8) / 256, 256, 0, stream>>>((const float4*)x, (uint4*)x0b);
  // 3. combined transposed weight, bf16
  build_wct_kernel<<<dim3(24, 24), 256, 0, stream>>>(expert_w, ws_gates, ws_idx, wct);
  // 4. GEMM -> out[0] (adds the +1.0)
  gemm_kernel<<<dim3(L_SEQ / 128, H_DIM / 128), 256, 0, stream>>>(x0b, wct, out);
  // 5. batches 1..15 = 1.0
  const size_t n4 = (size_t)(B_BATCH - 1) * L_SEQ * H_DIM / 4;
  fill_ones_kernel<<<2048, 256, 0, stream>>>((float4*)(out + (size_t)L_SEQ * H_DIM), n4);
}

// Round 2
// 119.092 us; speedup vs baseline: 1.3241x; 1.3241x over previous
//
#include <hip/hip_runtime.h>
#include <hip/hip_bf16.h>

typedef __attribute__((ext_vector_type(8))) short short8;
typedef __attribute__((ext_vector_type(4))) float f32x4;

#define H_DIM 768
#define E_EXP 16
#define T_TASK 8
#define KSEL 4
#define L_SEQ 8192
#define B_BATCH 16
#define EW_STRIDE (768*768)

#define CVT_BLOCKS 3072           // (8192*768/8)/256 uint4 stores
#define FILL1_BLOCKS 1280         // batches 1..8 in K1
#define GEMM_BLOCKS 384           // 64 x 6 tiles of 128x128
#define FILL3_BLOCKS 1152         // batches 9..15 in K3

// ---------------------------------------------------------------- K1 --------
// block 0: gating; blocks 1..CVT_BLOCKS: x0 -> bf16; rest: fill batches 1..8
__global__ __launch_bounds__(256) void k1_gating_cvt_fill(
    const float* __restrict__ task_full,
    const float* __restrict__ gate_w,
    const float* __restrict__ gate_b,
    float* __restrict__ out_tail,
    float* __restrict__ ws_gates,
    int*   __restrict__ ws_idx,
    const float4* __restrict__ x,
    uint4* __restrict__ xb,
    float4* __restrict__ fill_p, size_t fill_n4) {
  const int bid = blockIdx.x;
  const int tid = threadIdx.x;
  if (bid == 0) {
    // ---- gating ----
    __shared__ float silu_s[T_TASK * H_DIM];
    __shared__ float logits[T_TASK][E_EXP];
    for (int i = tid; i < T_TASK * H_DIM; i += 256) {
      float v = task_full[i];
      silu_s[i] = v / (1.f + expf(-v));
    }
    __syncthreads();
    if (tid < T_TASK * E_EXP) {
      const int t = tid >> 4, e = tid & 15;
      float a0 = 0.f, a1 = 0.f, a2 = 0.f, a3 = 0.f;
      const float* sl = &silu_s[t * H_DIM];
      for (int h = 0; h < H_DIM; h += 4) {
        a0 += sl[h]     * gate_w[(h)     * E_EXP + e];
        a1 += sl[h + 1] * gate_w[(h + 1) * E_EXP + e];
        a2 += sl[h + 2] * gate_w[(h + 2) * E_EXP + e];
        a3 += sl[h + 3] * gate_w[(h + 3) * E_EXP + e];
      }
      logits[t][e] = (a0 + a1) + (a2 + a3) + gate_b[e];
    }
    __syncthreads();
    if (tid < T_TASK) {
      const int t = tid;
      float p[E_EXP];
      float m = -1e30f;
      for (int e = 0; e < E_EXP; ++e) m = fmaxf(m, logits[t][e]);
      float s = 0.f;
      for (int e = 0; e < E_EXP; ++e) { p[e] = expf(logits[t][e] - m); s += p[e]; }
      const float inv = 1.f / s;
      for (int e = 0; e < E_EXP; ++e) p[e] *= inv;
      bool used[E_EXP];
      for (int e = 0; e < E_EXP; ++e) used[e] = false;
      float g[KSEL]; int sel[KSEL];
      for (int k = 0; k < KSEL; ++k) {
        float bv = -1.f; int bi = 0;
        for (int e = 0; e < E_EXP; ++e)
          if (!used[e] && p[e] > bv) { bv = p[e]; bi = e; }
        used[bi] = true; sel[k] = bi; g[k] = bv;
      }
      for (int e = 0; e < E_EXP; ++e)
        out_tail[E_EXP + t * E_EXP + e] = used[e] ? 1.f : 0.f;
      if (t == 0) {
        for (int e = 0; e < E_EXP; ++e) out_tail[e] = p[e];
        for (int k = 0; k < KSEL; ++k) { ws_gates[k] = g[k]; ws_idx[k] = sel[k]; }
      }
    }
  } else if (bid <= CVT_BLOCKS) {
    // ---- x0 -> bf16 ----
    const int i = (bid - 1) * 256 + tid;  // one uint4 = 8 bf16
    const float4 a = x[2 * i];
    const float4 b = x[2 * i + 1];
    alignas(16) __hip_bfloat16 h[8];
    h[0] = __float2bfloat16(a.x); h[1] = __float2bfloat16(a.y);
    h[2] = __float2bfloat16(a.z); h[3] = __float2bfloat16(a.w);
    h[4] = __float2bfloat16(b.x); h[5] = __float2bfloat16(b.y);
    h[6] = __float2bfloat16(b.z); h[7] = __float2bfloat16(b.w);
    xb[i] = *(const uint4*)h;
  } else {
    // ---- fill batches 1..8 ----
    const int fb = bid - 1 - CVT_BLOCKS;
    size_t i = (size_t)fb * 256 + tid;
    const size_t stride = (size_t)FILL1_BLOCKS * 256;
    const float4 one = make_float4(1.f, 1.f, 1.f, 1.f);
    for (; i < fill_n4; i += stride) fill_p[i] = one;
  }
}

// ------------------------------------------------- combined weight (T) ------
// wct[o][d] = sum_k gates[k] * expert_w[idx[k]][d][o], bf16
__global__ void build_wct_kernel(const float* __restrict__ expert_w,
                                 const float* __restrict__ gates,
                                 const int* __restrict__ idx,
                                 __hip_bfloat16* __restrict__ wct) {
  __shared__ float tile[32][33];
  const int d0 = blockIdx.x * 32, o0 = blockIdx.y * 32;
  const float g0 = gates[0], g1 = gates[1], g2 = gates[2], g3 = gates[3];
  const size_t e0 = (size_t)idx[0] * EW_STRIDE;
  const size_t e1 = (size_t)idx[1] * EW_STRIDE;
  const size_t e2 = (size_t)idx[2] * EW_STRIDE;
  const size_t e3 = (size_t)idx[3] * EW_STRIDE;
  const int c = threadIdx.x & 31;
  const int r0 = threadIdx.x >> 5;  // 0..7
#pragma unroll
  for (int it = 0; it < 4; ++it) {
    const int rr = it * 8 + r0;  // d offset
    const size_t off = (size_t)(d0 + rr) * H_DIM + o0 + c;
    tile[rr][c] = g0 * expert_w[e0 + off] + g1 * expert_w[e1 + off] +
                  g2 * expert_w[e2 + off] + g3 * expert_w[e3 + off];
  }
  __syncthreads();
#pragma unroll
  for (int it = 0; it < 4; ++it) {
    const int rr = it * 8 + r0;  // o offset
    wct[(size_t)(o0 + rr) * H_DIM + d0 + c] = __float2bfloat16(tile[c][rr]);
  }
}

// ---------------------------------------------------------------- K3 --------
__device__ __forceinline__ void gload_lds16(const void* g, void* l) {
  __builtin_amdgcn_global_load_lds((const __attribute__((address_space(1))) void*)g,
                                   (__attribute__((address_space(3))) void*)l, 16, 0, 0);
}

// blocks < GEMM_BLOCKS: C[l][o] = 1 + sum_d A[l][d]*Bt[o][d]; rest: fill 9..15
__global__ __launch_bounds__(256) void k3_gemm_fill(
    const __hip_bfloat16* __restrict__ A,
    const __hip_bfloat16* __restrict__ Bt,
    float* __restrict__ C,
    float4* __restrict__ fill_p, size_t fill_n4) {
  const int bid = blockIdx.x;
  const int tid = threadIdx.x;
  if (bid < GEMM_BLOCKS) {
    __shared__ __hip_bfloat16 As[128 * 32];
    __shared__ __hip_bfloat16 Bs[128 * 32];
    const int m0 = (bid & 63) * 128;        // consecutive ids share n0 -> share Bt
    const int n0 = (bid >> 6) * 128;
    const int lane = tid & 63;
    const int w = tid >> 6;
    const int wr = w >> 1, wc = w & 1;      // 2x2 wave grid, 64x64 each
    const int r = tid >> 2, s = tid & 3;    // staging: row, 16B chunk
    const __hip_bfloat16* ga = A  + (size_t)(m0 + r) * H_DIM + s * 8;
    const __hip_bfloat16* gb = Bt + (size_t)(n0 + r) * H_DIM + s * 8;
    f32x4 acc[4][4] = {};
    const int arow = wr * 64 + (lane & 15);
    const int brow = wc * 64 + (lane & 15);
    const int koff = (lane >> 4) * 8;  // same k mapping for A and B -> k-perm safe
    for (int k0 = 0; k0 < H_DIM; k0 += 32) {
      gload_lds16(ga + k0,               &As[tid * 8]);
      gload_lds16(ga + 64 * H_DIM + k0,  &As[2048 + tid * 8]);
      gload_lds16(gb + k0,               &Bs[tid * 8]);
      gload_lds16(gb + 64 * H_DIM + k0,  &Bs[2048 + tid * 8]);
      __syncthreads();
      short8 av[4], bv[4];
#pragma unroll
      for (int i = 0; i < 4; ++i) av[i] = *(const short8*)&As[(arow + i * 16) * 32 + koff];
#pragma unroll
      for (int j = 0; j < 4; ++j) bv[j] = *(const short8*)&Bs[(brow + j * 16) * 32 + koff];
#pragma unroll
      for (int i = 0; i < 4; ++i)
#pragma unroll
        for (int j = 0; j < 4; ++j)
          acc[i][j] = __builtin_amdgcn_mfma_f32_16x16x32_bf16(av[i], bv[j], acc[i][j], 0, 0, 0);
      __syncthreads();
    }
    const int crow0 = m0 + wr * 64 + (lane >> 4) * 4;
    const int ccol0 = n0 + wc * 64 + (lane & 15);
#pragma unroll
    for (int i = 0; i < 4; ++i)
#pragma unroll
      for (int j = 0; j < 4; ++j)
#pragma unroll
        for (int q = 0; q < 4; ++q)
          C[(size_t)(crow0 + i * 16 + q) * H_DIM + ccol0 + j * 16] = 1.0f + acc[i][j][q];
  } else {
    const int fb = bid - GEMM_BLOCKS;
    size_t i = (size_t)fb * 256 + tid;
    const size_t stride = (size_t)FILL3_BLOCKS * 256;
    const float4 one = make_float4(1.f, 1.f, 1.f, 1.f);
    for (; i < fill_n4; i += stride) fill_p[i] = one;
  }
}

// ---------------------------------------------------------------- launch ----
extern "C" void kernel_launch(void* const* d_in, const int* in_sizes, int n_in,
                              void* d_out, int out_size, void* d_ws, size_t ws_size,
                              hipStream_t stream) {
  const float* x         = (const float*)d_in[0];  // [16][8192][768]
  const float* task_full = (const float*)d_in[1];  // [8][768]
  const float* gate_w    = (const float*)d_in[2];  // [768][16]
  const float* gate_b    = (const float*)d_in[3];  // [16]
  const float* expert_w  = (const float*)d_in[4];  // [16][768][768]
  float* out = (float*)d_out;

  const size_t n_out_main = (size_t)B_BATCH * L_SEQ * H_DIM;  // 100663296
  float* out_tail = out + n_out_main;

  float* ws_gates = (float*)d_ws;
  int*   ws_idx   = (int*)((char*)d_ws + 16);
  __hip_bfloat16* wct = (__hip_bfloat16*)((char*)d_ws + 512);
  __hip_bfloat16* x0b = (__hip_bfloat16*)((char*)d_ws + 512 + (size_t)EW_STRIDE * 2);

  // K1: gating | x0->bf16 | fill batches 1..8
  const size_t fill1_n4 = (size_t)8 * L_SEQ * H_DIM / 4;
  k1_gating_cvt_fill<<<1 + CVT_BLOCKS + FILL1_BLOCKS, 256, 0, stream>>>(
      task_full, gate_w, gate_b, out_tail, ws_gates, ws_idx,
      (const float4*)x, (uint4*)x0b,
      (float4*)(out + (size_t)1 * L_SEQ * H_DIM), fill1_n4);

  // K2: combined transposed weight, bf16 (depends on gating)
  build_wct_kernel<<<dim3(24, 24), 256, 0, stream>>>(expert_w, ws_gates, ws_idx, wct);

  // K3: GEMM -> out[0] (adds +1.0) | fill batches 9..15
  const size_t fill3_n4 = (size_t)7 * L_SEQ * H_DIM / 4;
  k3_gemm_fill<<<GEMM_BLOCKS + FILL3_BLOCKS, 256, 0, stream>>>(
      x0b, wct, out,
      (float4*)(out + (size_t)9 * L_SEQ * H_DIM), fill3_n4);
}